// Round 11
// baseline (256.452 us; speedup 1.0000x reference)
//
#include <hip/hip_runtime.h>
#include <math.h>

// Clockwork RNN, B=512 T=192 DX=32 DH1=256 DH2=512 DY=4
// R10 = R9 structure with the REAL fix: launch_bounds back to (512,2).
// R9's (512,4) forced VGPR alloc to 64 -> W fragments spilled to scratch
// (30ms first dispatch, 2x regression). With (512,2) the compiler allocates
// ~76-90 VGPR naturally (R8 proof); since 76 <= 128 and LDS 37KB*2 <= 160KB,
// the HW co-schedules TWO independent blocks per CU (4 waves/SIMD) with
// separate barriers -> block A computes while block B waits.
//  - 512 blocks x (4 batch rows, one y) x 512 thr.
//  - lane-half epilogue split: r<8 lanes finish tile0, r>=8 finish tile1 ->
//    one 4-wide tanh+pack chain serves both tiles; single ds_write_b64;
//    clockwork carry folded via early read + select.
//  - h fp16 single array (R7), single fp16 W registers (R8), k-split dual
//    accumulator chains, 1 barrier/step, x register prefetch, W fragments
//    FULLY UNROLLED (R2 scratch-demotion lesson).

#define TT    192
#define DXX   32
#define DH1   256
#define DH2   512
#define NY    4
#define ROWS4 4
#define PADK  264   // row stride in fp16 elems (528B)

typedef _Float16 f16x8 __attribute__((ext_vector_type(8)));
typedef __attribute__((ext_vector_type(4))) float f32x4;
typedef __attribute__((ext_vector_type(2))) int   i32x2;
typedef __attribute__((ext_vector_type(4))) int   i32x4;

template<int N> struct IC { static constexpr int v = N; };

__device__ __forceinline__ unsigned pkrtz(float a, float b) {
    unsigned d;
    asm("v_cvt_pkrtz_f16_f32 %0, %1, %2" : "=v"(d) : "v"(a), "v"(b));
    return d;   // lo16 = f16(a), hi16 = f16(b), RTZ (x input only)
}
__device__ __forceinline__ unsigned short f16bits(_Float16 h) {
    union { _Float16 f; unsigned short u; } c; c.f = h; return c.u;
}
__device__ __forceinline__ float fast_tanh(float v) {
    float t = __builtin_amdgcn_exp2f(v * 2.885390081777927f);
    return fmaf(-2.f, __builtin_amdgcn_rcpf(t + 1.f), 1.f);
}

__global__ __launch_bounds__(512, 2) void cwrnn_mfma10(
    const float* __restrict__ x,     // [B,T,DX]
    const float* __restrict__ w_x,   // [DY,DX,DH1]
    const float* __restrict__ w_h,   // [DY,DH1,DH1]
    const float* __restrict__ bias,  // [DY,DH1]
    const float* __restrict__ W1,    // [DY,DH1,DH2]
    const float* __restrict__ b1,    // [DY,DH2]
    const float* __restrict__ W2,    // [DY,DH2]
    const float* __restrict__ b2,    // [DY]
    float* __restrict__ out)         // [B,DY]
{
    __shared__ _Float16 hb[2][ROWS4 * PADK];   // h fp16, [buf][row][k]
    __shared__ float red[8][ROWS4];
    __shared__ float scratch[DXX * DH1];       // 32KB staging; reused as hT

    const int t    = threadIdx.x;
    const int lane = t & 63;
    const int w    = t >> 6;        // wave 0..7; tiles {w, 8+w}
    const int r    = lane & 15;
    const int rb   = r & 3;         // batch row (4-way duplicated)
    const int q    = lane >> 4;
    const int y    = blockIdx.x & 3;
    const int b0   = (blockIdx.x >> 2) * ROWS4;

    const float* wx_g = w_x + (size_t)y * DXX * DH1;
    const float* wh_g = w_h + (size_t)y * DH1 * DH1;

    for (int i = t; i < ROWS4 * PADK; i += 512) hb[0][i] = (_Float16)0.f;

    // ---- w_x fragments: wave w -> tiles {w, 8+w}; single fp16 ----
    f16x8 wxf[2];
    for (int i = t * 4; i < DXX * DH1; i += 2048)
        *(f32x4*)&scratch[i] = *(const f32x4*)&wx_g[i];
    __syncthreads();
    #pragma unroll
    for (int m = 0; m < 2; ++m) {
        f16x8 vh;
        #pragma unroll
        for (int jj = 0; jj < 8; ++jj)
            vh[jj] = (_Float16)scratch[(q * 8 + jj) * DH1 + ((m * 8 + w) << 4) + r];
        wxf[m] = vh;
    }
    __syncthreads();

    // ---- w_h fragments: 8 ktiles x 2 mtiles, single fp16. FULLY UNROLLED
    // (runtime index -> scratch demotion; R2 lesson). ----
    f16x8 whf[8][2];
    #pragma unroll
    for (int kt = 0; kt < 8; ++kt) {
        for (int i = t * 4; i < 32 * DH1; i += 2048)
            *(f32x4*)&scratch[i] = *(const f32x4*)&wh_g[kt * 32 * DH1 + i];
        __syncthreads();
        #pragma unroll
        for (int m = 0; m < 2; ++m) {
            f16x8 vh;
            #pragma unroll
            for (int jj = 0; jj < 8; ++jj)
                vh[jj] = (_Float16)scratch[(q * 8 + jj) * DH1 + ((m * 8 + w) << 4) + r];
            whf[kt][m] = vh;
        }
        __syncthreads();
    }

    f32x4 bias4[2];
    #pragma unroll
    for (int m = 0; m < 2; ++m)
        #pragma unroll
        for (int rr = 0; rr < 4; ++rr)
            bias4[m][rr] = bias[y * DH1 + ((m * 8 + w) << 4) + q * 4 + rr];

    // ---- per-lane LDS pointers ----
    const _Float16* hrd[2] = { &hb[0][rb * PADK] + q * 8,
                               &hb[1][rb * PADK] + q * 8 };
    // lane-half split write/carry address: r<8 -> tile w, r>=8 -> tile 8+w
    const int tile_off = ((r < 8) ? w : 8 + w) << 4;
    _Float16* hws[2] = { &hb[0][rb * PADK + tile_off + q * 4],
                         &hb[1][rb * PADK + tile_off + q * 4] };
    const bool wlane = ((r & 7) < 4);   // unique-writer lanes

    const float* xrow = x + (size_t)(b0 + rb) * TT * DXX + q * 8;
    f32x4 cxa = *(const f32x4*)&xrow[0];
    f32x4 cxb = *(const f32x4*)&xrow[4];

    // ---- one recurrence step ----
    auto body = [&](int j, auto SC, int cur) {
        constexpr int S  = SC.v;                       // 0:NC=128 1:192 2:256
        constexpr int NF = (S == 0) ? 16 : (S == 1) ? 24 : 32;
        const bool m1act = (S == 2) || (S == 1 && w < 4);

        // prefetch next step's x
        const int jn = (j + 1 < TT) ? j + 1 : j;
        const f32x4 pxa = *(const f32x4*)&xrow[jn * DXX];
        const f32x4 pxb = *(const f32x4*)&xrow[jn * DXX + 4];

        // clockwork carry pre-read (old tile1 value for r>=8 lanes)
        i32x2 old1;
        if (!m1act) old1 = *(const i32x2*)(hws[cur]);

        // x B-fragment, fp16 (quad-uniform feature mask)
        f16x8 xf;
        if (q * 8 < NF) {
            union { i32x4 i; f16x8 h; } ux;
            ux.i = (i32x4){ (int)pkrtz(cxa[0], cxa[1]), (int)pkrtz(cxa[2], cxa[3]),
                            (int)pkrtz(cxb[0], cxb[1]), (int)pkrtz(cxb[2], cxb[3]) };
            xf = ux.h;
        } else {
            xf = (f16x8)(_Float16)0.f;
        }

        const _Float16* hp = hrd[cur];

        // k-split accumulators: kt0-3 -> a, kt4-7 + x -> b (2 indep chains)
        f32x4 a0a = bias4[0], a0b = {0,0,0,0};
        f32x4 a1a = bias4[1], a1b = {0,0,0,0};

        #pragma unroll
        for (int kt = 0; kt < 4; ++kt) {
            const f16x8 hv0 = *(const f16x8*)(hp + kt * 32);
            const f16x8 hv1 = *(const f16x8*)(hp + (kt + 4) * 32);
            a0a = __builtin_amdgcn_mfma_f32_16x16x32_f16(whf[kt][0], hv0, a0a, 0, 0, 0);
            a0b = __builtin_amdgcn_mfma_f32_16x16x32_f16(whf[kt + 4][0], hv1, a0b, 0, 0, 0);
            if (m1act) {
                a1a = __builtin_amdgcn_mfma_f32_16x16x32_f16(whf[kt][1], hv0, a1a, 0, 0, 0);
                a1b = __builtin_amdgcn_mfma_f32_16x16x32_f16(whf[kt + 4][1], hv1, a1b, 0, 0, 0);
            }
        }
        a0b = __builtin_amdgcn_mfma_f32_16x16x32_f16(wxf[0], xf, a0b, 0, 0, 0);
        if (m1act)
            a1b = __builtin_amdgcn_mfma_f32_16x16x32_f16(wxf[1], xf, a1b, 0, 0, 0);

        // ---- epilogue: lane-half tile select -> ONE tanh/pack pipeline ----
        {
            const f32x4 s0 = a0a + a0b;
            f32x4 sel;
            if (m1act) {
                const f32x4 s1 = a1a + a1b;
                sel[0] = (r < 8) ? s0[0] : s1[0];
                sel[1] = (r < 8) ? s0[1] : s1[1];
                sel[2] = (r < 8) ? s0[2] : s1[2];
                sel[3] = (r < 8) ? s0[3] : s1[3];
            } else {
                sel = s0;   // r>=8 lanes produce garbage; overridden by old1
            }
            const unsigned short h0 = f16bits((_Float16)fast_tanh(sel[0]));
            const unsigned short h1 = f16bits((_Float16)fast_tanh(sel[1]));
            const unsigned short h2 = f16bits((_Float16)fast_tanh(sel[2]));
            const unsigned short h3 = f16bits((_Float16)fast_tanh(sel[3]));
            i32x2 wv = (i32x2){ (int)(h0 | ((unsigned)h1 << 16)),
                                (int)(h2 | ((unsigned)h3 << 16)) };
            if (!m1act && r >= 8) wv = old1;   // clockwork carry
            if (wlane) *(i32x2*)(hws[cur ^ 1]) = wv;
        }
        __syncthreads();
        cxa = pxa; cxb = pxb;
    };

    // ---- main loop ----
    for (int j = 0; j < TT; j += 4) {
        body(j + 0, IC<0>{}, 0);   // jp odd           -> NC=128
        body(j + 1, IC<1>{}, 1);   // jp%2==0, %4!=0   -> NC=192
        body(j + 2, IC<0>{}, 0);   // jp odd           -> NC=128
        body(j + 3, IC<2>{}, 1);   // jp%4==0          -> NC=256
    }
    // final h in buffer 0

    // ---- rebuild h fp32, transposed [k][row] ----
    float* hT = scratch;
    for (int i = t; i < DH1 * ROWS4; i += 512) {
        const int row = i & 3, k = i >> 2;
        hT[k * ROWS4 + row] = (float)hb[0][row * PADK + k];
    }
    __syncthreads();

    // ---- head: hid = relu(h @ W1 + b1); y = hid @ W2 + b2 ----
    const float* W1_g = W1 + (size_t)y * DH1 * DH2;
    float a0[4];
    #pragma unroll
    for (int m = 0; m < 4; ++m) a0[m] = 0.f;
    for (int k = 0; k < DH1; ++k) {
        const float wv = W1_g[(size_t)k * DH2 + t];
        const f32x4 hA = *(const f32x4*)&hT[k * ROWS4];
        a0[0] += hA[0] * wv; a0[1] += hA[1] * wv;
        a0[2] += hA[2] * wv; a0[3] += hA[3] * wv;
    }
    {
        const float b1v = b1[y * DH2 + t];
        const float w2v = W2[y * DH2 + t];
        float p[4];
        #pragma unroll
        for (int m = 0; m < 4; ++m)
            p[m] = fmaxf(a0[m] + b1v, 0.f) * w2v;
        #pragma unroll
        for (int m = 0; m < 4; ++m) {
            float v = p[m];
            for (int off = 32; off > 0; off >>= 1) v += __shfl_down(v, off);
            if (lane == 0) red[w][m] = v;
        }
    }
    __syncthreads();
    if (t < ROWS4) {
        float s = b2[y];
        #pragma unroll
        for (int ww = 0; ww < 8; ++ww) s += red[ww][t];
        out[(size_t)(b0 + t) * NY + y] = s;
    }
}

extern "C" void kernel_launch(void* const* d_in, const int* in_sizes, int n_in,
                              void* d_out, int out_size, void* d_ws, size_t ws_size,
                              hipStream_t stream) {
    const float* x   = (const float*)d_in[0];
    const float* w_x = (const float*)d_in[1];
    const float* w_h = (const float*)d_in[2];
    const float* b   = (const float*)d_in[3];
    const float* W1  = (const float*)d_in[4];
    const float* b1  = (const float*)d_in[5];
    const float* W2  = (const float*)d_in[6];
    const float* b2  = (const float*)d_in[7];
    float* out = (float*)d_out;

    dim3 grid(512), block(512);
    hipLaunchKernelGGL(cwrnn_mfma10, grid, block, 0, stream,
                       x, w_x, w_h, b, W1, b1, W2, b2, out);
}

// Round 12
// 154.705 us; speedup vs baseline: 1.6577x; 1.6577x over previous
//
#include <hip/hip_runtime.h>
#include <math.h>

// Clockwork RNN, B=512 T=192 DX=32 DH1=256 DH2=512 DY=4
// R11 = R8 shape (256 blocks x 8 rows x 8 waves, fp16 h + fp16 W in regs)
// with the LDS pipe + epilogue attacked:
//  - kt-rotation layout: h row rb's k-block kt stored at ((kt+rb)&3)*64B
//    (row stride 272B) -> B-frag ds_read_b128 slot = rb+q+4*par(kt+rb),
//    distinct across rb => kills the 4-way bank conflict of R8's layout.
//  - h split: hA = cols 0-127 (double-buffered, toggles every step),
//    hB = cols 128-255 (toggles only on S1/S2 steps) -> NO clockwork carry
//    on S0 steps (half of all steps); S1 carry = 4 waves only.
//    kt0-3 -> hA, kt4-7 -> hB matches the k-split accumulator chains.
//  - lane-half epilogue: r<8 lanes finish tile0, r>=8 finish tile1 ->
//    4 tanh/lane (was 8), one b64 write for the whole wave.
// W fragments FULLY UNROLLED into registers (R2 lesson); natural VGPR fit,
// launch_bounds(512,2) (R9/R10 lesson: never force occupancy via bounds).

#define TT    192
#define DXX   32
#define DH1   256
#define DH2   512
#define NY    4
#define ROWS8 8
#define RS    136    // shorts per h row (272B = 17 x 16B chunks, odd)
#define BUFS  1088   // shorts per buffer (8*136); A0@0 A1@1088 B0@2176 B1@3264

typedef _Float16 f16x8 __attribute__((ext_vector_type(8)));
typedef __attribute__((ext_vector_type(4))) float f32x4;
typedef __attribute__((ext_vector_type(2))) int   i32x2;
typedef __attribute__((ext_vector_type(4))) int   i32x4;

template<int N> struct IC { static constexpr int v = N; };

__device__ __forceinline__ unsigned pkrtz(float a, float b) {
    unsigned d;
    asm("v_cvt_pkrtz_f16_f32 %0, %1, %2" : "=v"(d) : "v"(a), "v"(b));
    return d;   // lo16 = f16(a), hi16 = f16(b), RTZ (x input only)
}
__device__ __forceinline__ unsigned short f16bits(_Float16 h) {
    union { _Float16 f; unsigned short u; } c; c.f = h; return c.u;
}
__device__ __forceinline__ float fast_tanh(float v) {
    float t = __builtin_amdgcn_exp2f(v * 2.885390081777927f);
    return fmaf(-2.f, __builtin_amdgcn_rcpf(t + 1.f), 1.f);
}

__global__ __launch_bounds__(512, 2) void cwrnn_mfma11(
    const float* __restrict__ x,     // [B,T,DX]
    const float* __restrict__ w_x,   // [DY,DX,DH1]
    const float* __restrict__ w_h,   // [DY,DH1,DH1]
    const float* __restrict__ bias,  // [DY,DH1]
    const float* __restrict__ W1,    // [DY,DH1,DH2]
    const float* __restrict__ b1,    // [DY,DH2]
    const float* __restrict__ W2,    // [DY,DH2]
    const float* __restrict__ b2,    // [DY]
    float* __restrict__ out)         // [B,DY]
{
    __shared__ __align__(16) _Float16 harr[4 * BUFS];  // A0 A1 B0 B1, 8.5KB
    __shared__ float red[8][ROWS8];
    __shared__ float scratch[DXX * DH1];               // 32KB staging / hT

    const int t    = threadIdx.x;
    const int lane = t & 63;
    const int w    = t >> 6;        // wave 0..7; tile0 = cols w*16, tile1 = 128+w*16
    const int r    = lane & 15;
    const int rb   = r & 7;         // batch row (r, r+8 duplicate -> broadcast)
    const int q    = lane >> 4;
    const int y    = blockIdx.x & 3;
    const int b0   = (blockIdx.x >> 2) * ROWS8;

    const float* wx_g = w_x + (size_t)y * DXX * DH1;
    const float* wh_g = w_h + (size_t)y * DH1 * DH1;

    for (int i = t; i < 4 * BUFS; i += 512) harr[i] = (_Float16)0.f;

    // ---- w_x fragments: wave w -> tiles {w, 8+w}; single fp16 ----
    f16x8 wxf[2];
    for (int i = t * 4; i < DXX * DH1; i += 2048)
        *(f32x4*)&scratch[i] = *(const f32x4*)&wx_g[i];
    __syncthreads();
    #pragma unroll
    for (int m = 0; m < 2; ++m) {
        f16x8 vh;
        #pragma unroll
        for (int jj = 0; jj < 8; ++jj)
            vh[jj] = (_Float16)scratch[(q * 8 + jj) * DH1 + ((m * 8 + w) << 4) + r];
        wxf[m] = vh;
    }
    __syncthreads();

    // ---- w_h fragments: 8 ktiles x 2 mtiles, fp16. FULLY UNROLLED ----
    f16x8 whf[8][2];
    #pragma unroll
    for (int kt = 0; kt < 8; ++kt) {
        for (int i = t * 4; i < 32 * DH1; i += 2048)
            *(f32x4*)&scratch[i] = *(const f32x4*)&wh_g[kt * 32 * DH1 + i];
        __syncthreads();
        #pragma unroll
        for (int m = 0; m < 2; ++m) {
            f16x8 vh;
            #pragma unroll
            for (int jj = 0; jj < 8; ++jj)
                vh[jj] = (_Float16)scratch[(q * 8 + jj) * DH1 + ((m * 8 + w) << 4) + r];
            whf[kt][m] = vh;
        }
        __syncthreads();
    }

    f32x4 bias4[2];
    #pragma unroll
    for (int m = 0; m < 2; ++m)
        #pragma unroll
        for (int rr = 0; rr < 4; ++rr)
            bias4[m][rr] = bias[y * DH1 + ((m * 8 + w) << 4) + q * 4 + rr];

    // ---- loop-invariant LDS offsets (shorts) ----
    // read: logical kt (0-3 within buffer) at rotated slot ((kt+rb)&3)
    int roff[4];
    #pragma unroll
    for (int kt = 0; kt < 4; ++kt)
        roff[kt] = rb * RS + (((kt + rb) & 3) << 5) + q * 8;
    // write: tile col w*16+q*4 -> ktw = w>>1, within = (w&1)*16 + q*4
    const int woff = rb * RS + (((((unsigned)w >> 1) + rb) & 3) << 5)
                   + ((w & 1) << 4) + (q << 2);

    const float* xrow = x + (size_t)(b0 + rb) * TT * DXX + q * 8;
    f32x4 cxa = *(const f32x4*)&xrow[0];
    f32x4 cxb = *(const f32x4*)&xrow[4];

    // ---- one recurrence step; RA/RB = read buffer indices (compile-time) ----
    auto body = [&](auto SC, auto RAC, auto RBC, int j) {
        constexpr int S  = SC.v;                       // 0:NC=128 1:192 2:256
        constexpr int RA = RAC.v, RB = RBC.v;
        constexpr int NF = (S == 0) ? 16 : (S == 1) ? 24 : 32;
        const bool m1act = (S == 2) || (S == 1 && w < 4);

        // prefetch next step's x
        const int jn = (j + 1 < TT) ? j + 1 : j;
        const f32x4 pxa = *(const f32x4*)&xrow[jn * DXX];
        const f32x4 pxb = *(const f32x4*)&xrow[jn * DXX + 4];

        // x B-fragment, fp16 (quad-uniform feature mask)
        f16x8 xf;
        if (q * 8 < NF) {
            union { i32x4 i; f16x8 h; } ux;
            ux.i = (i32x4){ (int)pkrtz(cxa[0], cxa[1]), (int)pkrtz(cxa[2], cxa[3]),
                            (int)pkrtz(cxb[0], cxb[1]), (int)pkrtz(cxb[2], cxb[3]) };
            xf = ux.h;
        } else {
            xf = (f16x8)(_Float16)0.f;
        }

        // chains: a = kt0-3 (hA), b = x + kt4-7 (hB)
        f32x4 a0a = bias4[0];
        f32x4 a0b = __builtin_amdgcn_mfma_f32_16x16x32_f16(wxf[0], xf,
                        (f32x4){0.f, 0.f, 0.f, 0.f}, 0, 0, 0);
        f32x4 a1a = bias4[1];
        f32x4 a1b = {0.f, 0.f, 0.f, 0.f};
        if (m1act)
            a1b = __builtin_amdgcn_mfma_f32_16x16x32_f16(wxf[1], xf, a1b, 0, 0, 0);

        #pragma unroll
        for (int kt = 0; kt < 4; ++kt) {
            const f16x8 hv0 = *(const f16x8*)&harr[RA * BUFS + roff[kt]];
            const f16x8 hv1 = *(const f16x8*)&harr[2 * BUFS + RB * BUFS + roff[kt]];
            a0a = __builtin_amdgcn_mfma_f32_16x16x32_f16(whf[kt][0], hv0, a0a, 0, 0, 0);
            a0b = __builtin_amdgcn_mfma_f32_16x16x32_f16(whf[kt + 4][0], hv1, a0b, 0, 0, 0);
            if (m1act) {
                a1a = __builtin_amdgcn_mfma_f32_16x16x32_f16(whf[kt][1], hv0, a1a, 0, 0, 0);
                a1b = __builtin_amdgcn_mfma_f32_16x16x32_f16(whf[kt + 4][1], hv1, a1b, 0, 0, 0);
            }
        }

        // ---- epilogue: lane-half split ----
        const f32x4 s0 = a0a + a0b;
        if (S == 0) {
            // only hA updates; r>=8 lanes idle (no carry needed: hB untouched)
            if (r < 8) {
                const unsigned short h0 = f16bits((_Float16)fast_tanh(s0[0]));
                const unsigned short h1 = f16bits((_Float16)fast_tanh(s0[1]));
                const unsigned short h2 = f16bits((_Float16)fast_tanh(s0[2]));
                const unsigned short h3 = f16bits((_Float16)fast_tanh(s0[3]));
                *(i32x2*)&harr[(RA ^ 1) * BUFS + woff] =
                    (i32x2){ (int)(h0 | ((unsigned)h1 << 16)),
                             (int)(h2 | ((unsigned)h3 << 16)) };
            }
        } else if (S == 2 ) {
            const f32x4 s1 = a1a + a1b;
            f32x4 sel;
            sel[0] = (r < 8) ? s0[0] : s1[0];
            sel[1] = (r < 8) ? s0[1] : s1[1];
            sel[2] = (r < 8) ? s0[2] : s1[2];
            sel[3] = (r < 8) ? s0[3] : s1[3];
            const unsigned short h0 = f16bits((_Float16)fast_tanh(sel[0]));
            const unsigned short h1 = f16bits((_Float16)fast_tanh(sel[1]));
            const unsigned short h2 = f16bits((_Float16)fast_tanh(sel[2]));
            const unsigned short h3 = f16bits((_Float16)fast_tanh(sel[3]));
            const int wa = (r < 8) ? (RA ^ 1) * BUFS + woff
                                   : 2 * BUFS + (RB ^ 1) * BUFS + woff;
            *(i32x2*)&harr[wa] = (i32x2){ (int)(h0 | ((unsigned)h1 << 16)),
                                          (int)(h2 | ((unsigned)h3 << 16)) };
        } else {  // S == 1
            if (w < 4) {
                const f32x4 s1 = a1a + a1b;
                f32x4 sel;
                sel[0] = (r < 8) ? s0[0] : s1[0];
                sel[1] = (r < 8) ? s0[1] : s1[1];
                sel[2] = (r < 8) ? s0[2] : s1[2];
                sel[3] = (r < 8) ? s0[3] : s1[3];
                const unsigned short h0 = f16bits((_Float16)fast_tanh(sel[0]));
                const unsigned short h1 = f16bits((_Float16)fast_tanh(sel[1]));
                const unsigned short h2 = f16bits((_Float16)fast_tanh(sel[2]));
                const unsigned short h3 = f16bits((_Float16)fast_tanh(sel[3]));
                const int wa = (r < 8) ? (RA ^ 1) * BUFS + woff
                                       : 2 * BUFS + (RB ^ 1) * BUFS + woff;
                *(i32x2*)&harr[wa] = (i32x2){ (int)(h0 | ((unsigned)h1 << 16)),
                                              (int)(h2 | ((unsigned)h3 << 16)) };
            } else {
                if (r < 8) {
                    const unsigned short h0 = f16bits((_Float16)fast_tanh(s0[0]));
                    const unsigned short h1 = f16bits((_Float16)fast_tanh(s0[1]));
                    const unsigned short h2 = f16bits((_Float16)fast_tanh(s0[2]));
                    const unsigned short h3 = f16bits((_Float16)fast_tanh(s0[3]));
                    *(i32x2*)&harr[(RA ^ 1) * BUFS + woff] =
                        (i32x2){ (int)(h0 | ((unsigned)h1 << 16)),
                                 (int)(h2 | ((unsigned)h3 << 16)) };
                } else {
                    // clockwork carry for hB cols 64-127 (waves 4-7)
                    *(i32x2*)&harr[2 * BUFS + (RB ^ 1) * BUFS + woff] =
                        *(const i32x2*)&harr[2 * BUFS + RB * BUFS + woff];
                }
            }
        }
        __syncthreads();
        cxa = pxa; cxb = pxb;
    };

    // ---- main loop: buffer schedule has period 4 (A: 0,1,0,1; B: 0,0,1,1) ----
    for (int j = 0; j < TT; j += 4) {
        body(IC<0>{}, IC<0>{}, IC<0>{}, j + 0);   // jp odd  NC=128: A0->A1
        body(IC<1>{}, IC<1>{}, IC<0>{}, j + 1);   // NC=192: A1->A0, B0->B1
        body(IC<0>{}, IC<0>{}, IC<1>{}, j + 2);   // NC=128: A0->A1
        body(IC<2>{}, IC<1>{}, IC<1>{}, j + 3);   // NC=256: A1->A0, B1->B0
    }
    // final h: hA in buffer 0, hB in buffer 0

    // ---- rebuild h fp32, transposed [k][row] ----
    float* hT = scratch;
    for (int i = t; i < DH1 * ROWS8; i += 512) {
        const int row = i & 7, k = i >> 3;
        float v;
        if (k < 128)
            v = (float)harr[row * RS + ((((k >> 5) + row) & 3) << 5) + (k & 31)];
        else
            v = (float)harr[2 * BUFS + row * RS
                            + (((((k - 128) >> 5) + row) & 3) << 5) + (k & 31)];
        hT[k * ROWS8 + row] = v;
    }
    __syncthreads();

    // ---- head: hid = relu(h @ W1 + b1); y = hid @ W2 + b2 ----
    const float* W1_g = W1 + (size_t)y * DH1 * DH2;
    float a0[8];
    #pragma unroll
    for (int m = 0; m < 8; ++m) a0[m] = 0.f;
    for (int k = 0; k < DH1; ++k) {
        const float wv = W1_g[(size_t)k * DH2 + t];
        const f32x4 hA = *(const f32x4*)&hT[k * ROWS8];
        const f32x4 hB = *(const f32x4*)&hT[k * ROWS8 + 4];
        a0[0] += hA[0] * wv; a0[1] += hA[1] * wv;
        a0[2] += hA[2] * wv; a0[3] += hA[3] * wv;
        a0[4] += hB[0] * wv; a0[5] += hB[1] * wv;
        a0[6] += hB[2] * wv; a0[7] += hB[3] * wv;
    }
    {
        const float b1v = b1[y * DH2 + t];
        const float w2v = W2[y * DH2 + t];
        float p[8];
        #pragma unroll
        for (int m = 0; m < 8; ++m)
            p[m] = fmaxf(a0[m] + b1v, 0.f) * w2v;
        #pragma unroll
        for (int m = 0; m < 8; ++m) {
            float v = p[m];
            for (int off = 32; off > 0; off >>= 1) v += __shfl_down(v, off);
            if (lane == 0) red[w][m] = v;
        }
    }
    __syncthreads();
    if (t < ROWS8) {
        float s = b2[y];
        #pragma unroll
        for (int ww = 0; ww < 8; ++ww) s += red[ww][t];
        out[(size_t)(b0 + t) * NY + y] = s;
    }
}

extern "C" void kernel_launch(void* const* d_in, const int* in_sizes, int n_in,
                              void* d_out, int out_size, void* d_ws, size_t ws_size,
                              hipStream_t stream) {
    const float* x   = (const float*)d_in[0];
    const float* w_x = (const float*)d_in[1];
    const float* w_h = (const float*)d_in[2];
    const float* b   = (const float*)d_in[3];
    const float* W1  = (const float*)d_in[4];
    const float* b1  = (const float*)d_in[5];
    const float* W2  = (const float*)d_in[6];
    const float* b2  = (const float*)d_in[7];
    float* out = (float*)d_out;

    dim3 grid(256), block(512);
    hipLaunchKernelGGL(cwrnn_mfma11, grid, block, 0, stream,
                       x, w_x, w_h, b, W1, b1, W2, b2, out);
}

// Round 13
// 141.109 us; speedup vs baseline: 1.8174x; 1.0963x over previous
//
#include <hip/hip_runtime.h>
#include <math.h>

// Clockwork RNN, B=512 T=192 DX=32 DH1=256 DH2=512 DY=4
// R12 = R8 base + three targeted latency/VALU edits:
//  1. lane-half epilogue with carry PRE-READ: r<8 lanes finish tile0, r>=8
//     finish tile1 -> 4 tanh/lane (R11 proved the VALU cut); carry handled by
//     pre-reading old tile1 before MFMA + cndmask into the single b64 write
//     (all 64 lanes write unique 8B).
//  2. 3 independent MFMA chains per tile (kt%3) -> dependent-chain depth 5->3.
//  3. s_setprio(1) around the MFMA cluster.
// Everything else exactly R8: 256 blocks x 512 thr, h fp16 single array
// (PADK=264, dup-2 broadcast B-frag), fp16 W registers FULLY UNROLLED
// (R2 lesson), double-buffered h, 1 barrier/step, x register prefetch,
// launch_bounds(512,2) (R9/R10 lesson: never force occupancy via bounds).

#define TT    192
#define DXX   32
#define DH1   256
#define DH2   512
#define NY    4
#define ROWS8 8
#define PADK  264   // row stride in fp16 elems (528B)

typedef _Float16 f16x8 __attribute__((ext_vector_type(8)));
typedef __attribute__((ext_vector_type(4))) float f32x4;
typedef __attribute__((ext_vector_type(2))) int   i32x2;
typedef __attribute__((ext_vector_type(4))) int   i32x4;

template<int N> struct IC { static constexpr int v = N; };

__device__ __forceinline__ unsigned pkrtz(float a, float b) {
    unsigned d;
    asm("v_cvt_pkrtz_f16_f32 %0, %1, %2" : "=v"(d) : "v"(a), "v"(b));
    return d;   // lo16 = f16(a), hi16 = f16(b)
}
__device__ __forceinline__ unsigned short f16bits(_Float16 h) {
    union { _Float16 f; unsigned short u; } c; c.f = h; return c.u;
}
__device__ __forceinline__ float fast_tanh(float v) {
    float t = __builtin_amdgcn_exp2f(v * 2.885390081777927f);
    return fmaf(-2.f, __builtin_amdgcn_rcpf(t + 1.f), 1.f);
}

__global__ __launch_bounds__(512, 2) void cwrnn_mfma12(
    const float* __restrict__ x,     // [B,T,DX]
    const float* __restrict__ w_x,   // [DY,DX,DH1]
    const float* __restrict__ w_h,   // [DY,DH1,DH1]
    const float* __restrict__ bias,  // [DY,DH1]
    const float* __restrict__ W1,    // [DY,DH1,DH2]
    const float* __restrict__ b1,    // [DY,DH2]
    const float* __restrict__ W2,    // [DY,DH2]
    const float* __restrict__ b2,    // [DY]
    float* __restrict__ out)         // [B,DY]
{
    __shared__ _Float16 hb[2][ROWS8 * PADK];   // h fp16, [buf][row][k]
    __shared__ float red[8][ROWS8];
    __shared__ float scratch[DXX * DH1];       // 32KB staging; reused as hT

    const int t    = threadIdx.x;
    const int lane = t & 63;
    const int w    = t >> 6;        // wave 0..7; tile0 = w, tile1 = 8+w
    const int r    = lane & 15;
    const int rb   = r & 7;         // batch row (r, r+8 duplicate -> broadcast)
    const int q    = lane >> 4;
    const int y    = blockIdx.x & 3;
    const int b0   = (blockIdx.x >> 2) * ROWS8;

    const float* wx_g = w_x + (size_t)y * DXX * DH1;
    const float* wh_g = w_h + (size_t)y * DH1 * DH1;

    for (int i = t; i < ROWS8 * PADK; i += 512) hb[0][i] = (_Float16)0.f;

    // ---- w_x fragments: wave w -> tiles {w, 8+w}; single fp16 ----
    f16x8 wxf[2];
    for (int i = t * 4; i < DXX * DH1; i += 2048)
        *(f32x4*)&scratch[i] = *(const f32x4*)&wx_g[i];
    __syncthreads();
    #pragma unroll
    for (int m = 0; m < 2; ++m) {
        f16x8 vh;
        #pragma unroll
        for (int jj = 0; jj < 8; ++jj)
            vh[jj] = (_Float16)scratch[(q * 8 + jj) * DH1 + ((m * 8 + w) << 4) + r];
        wxf[m] = vh;
    }
    __syncthreads();

    // ---- w_h fragments: 8 ktiles x 2 mtiles, single fp16. FULLY UNROLLED
    // (runtime index -> scratch demotion; R2 lesson). ----
    f16x8 whf[8][2];
    #pragma unroll
    for (int kt = 0; kt < 8; ++kt) {
        for (int i = t * 4; i < 32 * DH1; i += 2048)
            *(f32x4*)&scratch[i] = *(const f32x4*)&wh_g[kt * 32 * DH1 + i];
        __syncthreads();
        #pragma unroll
        for (int m = 0; m < 2; ++m) {
            f16x8 vh;
            #pragma unroll
            for (int jj = 0; jj < 8; ++jj)
                vh[jj] = (_Float16)scratch[(q * 8 + jj) * DH1 + ((m * 8 + w) << 4) + r];
            whf[kt][m] = vh;
        }
        __syncthreads();
    }

    f32x4 bias4[2];
    #pragma unroll
    for (int m = 0; m < 2; ++m)
        #pragma unroll
        for (int rr = 0; rr < 4; ++rr)
            bias4[m][rr] = bias[y * DH1 + ((m * 8 + w) << 4) + q * 4 + rr];

    // ---- per-lane LDS pointers ----
    const _Float16* hrd[2] = { &hb[0][rb * PADK] + q * 8,
                               &hb[1][rb * PADK] + q * 8 };
    // lane-half write/carry address: r<8 -> tile w, r>=8 -> tile 8+w
    const int tile_off = ((r < 8) ? w : 8 + w) << 4;
    _Float16* hws[2] = { &hb[0][rb * PADK + tile_off + q * 4],
                         &hb[1][rb * PADK + tile_off + q * 4] };

    const float* xrow = x + (size_t)(b0 + rb) * TT * DXX + q * 8;
    f32x4 cxa = *(const f32x4*)&xrow[0];
    f32x4 cxb = *(const f32x4*)&xrow[4];

    // ---- one recurrence step ----
    auto body = [&](int j, auto SC, int cur) {
        constexpr int S  = SC.v;                       // 0:NC=128 1:192 2:256
        constexpr int NF = (S == 0) ? 16 : (S == 1) ? 24 : 32;
        const bool m1act = (S == 2) || (S == 1 && w < 4);

        // prefetch next step's x
        const int jn = (j + 1 < TT) ? j + 1 : j;
        const f32x4 pxa = *(const f32x4*)&xrow[jn * DXX];
        const f32x4 pxb = *(const f32x4*)&xrow[jn * DXX + 4];

        // clockwork carry pre-read (old tile1 value, r>=8 lanes use it)
        i32x2 old1;
        if (!m1act) old1 = *(const i32x2*)(hws[cur]);

        // x B-fragment, fp16 (quad-uniform feature mask)
        f16x8 xf;
        if (q * 8 < NF) {
            union { i32x4 i; f16x8 h; } ux;
            ux.i = (i32x4){ (int)pkrtz(cxa[0], cxa[1]), (int)pkrtz(cxa[2], cxa[3]),
                            (int)pkrtz(cxb[0], cxb[1]), (int)pkrtz(cxb[2], cxb[3]) };
            xf = ux.h;
        } else {
            xf = (f16x8)(_Float16)0.f;
        }

        const _Float16* hp = hrd[cur];

        // 3 independent chains per tile: kt -> chain kt%3; x -> chain 2
        f32x4 c0 = bias4[0], c1 = {0,0,0,0}, c2 = {0,0,0,0};
        f32x4 d0 = bias4[1], d1 = {0,0,0,0}, d2 = {0,0,0,0};

        __builtin_amdgcn_s_setprio(1);
        #pragma unroll
        for (int kt = 0; kt < 8; ++kt) {
            const f16x8 hv = *(const f16x8*)(hp + kt * 32);
            if ((kt % 3) == 0)
                c0 = __builtin_amdgcn_mfma_f32_16x16x32_f16(whf[kt][0], hv, c0, 0, 0, 0);
            else if ((kt % 3) == 1)
                c1 = __builtin_amdgcn_mfma_f32_16x16x32_f16(whf[kt][0], hv, c1, 0, 0, 0);
            else
                c2 = __builtin_amdgcn_mfma_f32_16x16x32_f16(whf[kt][0], hv, c2, 0, 0, 0);
            if (m1act) {
                if ((kt % 3) == 0)
                    d0 = __builtin_amdgcn_mfma_f32_16x16x32_f16(whf[kt][1], hv, d0, 0, 0, 0);
                else if ((kt % 3) == 1)
                    d1 = __builtin_amdgcn_mfma_f32_16x16x32_f16(whf[kt][1], hv, d1, 0, 0, 0);
                else
                    d2 = __builtin_amdgcn_mfma_f32_16x16x32_f16(whf[kt][1], hv, d2, 0, 0, 0);
            }
        }
        c2 = __builtin_amdgcn_mfma_f32_16x16x32_f16(wxf[0], xf, c2, 0, 0, 0);
        if (m1act)
            d2 = __builtin_amdgcn_mfma_f32_16x16x32_f16(wxf[1], xf, d2, 0, 0, 0);
        __builtin_amdgcn_s_setprio(0);

        // ---- epilogue: lane-half tile select -> ONE tanh/pack pipeline ----
        {
            const f32x4 s0 = (c0 + c1) + c2;
            f32x4 sel;
            if (m1act) {
                const f32x4 s1 = (d0 + d1) + d2;
                sel[0] = (r < 8) ? s0[0] : s1[0];
                sel[1] = (r < 8) ? s0[1] : s1[1];
                sel[2] = (r < 8) ? s0[2] : s1[2];
                sel[3] = (r < 8) ? s0[3] : s1[3];
            } else {
                sel = s0;   // r>=8 lanes' value overridden by old1 below
            }
            const unsigned short h0 = f16bits((_Float16)fast_tanh(sel[0]));
            const unsigned short h1 = f16bits((_Float16)fast_tanh(sel[1]));
            const unsigned short h2 = f16bits((_Float16)fast_tanh(sel[2]));
            const unsigned short h3 = f16bits((_Float16)fast_tanh(sel[3]));
            i32x2 wv = (i32x2){ (int)(h0 | ((unsigned)h1 << 16)),
                                (int)(h2 | ((unsigned)h3 << 16)) };
            if (!m1act && r >= 8) wv = old1;   // clockwork carry
            *(i32x2*)(hws[cur ^ 1]) = wv;      // all 64 lanes: unique 8B
        }
        __syncthreads();
        cxa = pxa; cxb = pxb;
    };

    // ---- main loop ----
    for (int j = 0; j < TT; j += 4) {
        body(j + 0, IC<0>{}, 0);   // jp odd           -> NC=128
        body(j + 1, IC<1>{}, 1);   // jp%2==0, %4!=0   -> NC=192
        body(j + 2, IC<0>{}, 0);   // jp odd           -> NC=128
        body(j + 3, IC<2>{}, 1);   // jp%4==0          -> NC=256
    }
    // final h in buffer 0

    // ---- rebuild h fp32, transposed [k][row] ----
    float* hT = scratch;
    for (int i = t; i < DH1 * ROWS8; i += 512) {
        const int row = i & 7, k = i >> 3;
        hT[k * ROWS8 + row] = (float)hb[0][row * PADK + k];
    }
    __syncthreads();

    // ---- head: hid = relu(h @ W1 + b1); y = hid @ W2 + b2 ----
    const float* W1_g = W1 + (size_t)y * DH1 * DH2;
    float a0[8];
    #pragma unroll
    for (int m = 0; m < 8; ++m) a0[m] = 0.f;
    for (int k = 0; k < DH1; ++k) {
        const float wv = W1_g[(size_t)k * DH2 + t];
        const f32x4 hA = *(const f32x4*)&hT[k * ROWS8];
        const f32x4 hB = *(const f32x4*)&hT[k * ROWS8 + 4];
        a0[0] += hA[0] * wv; a0[1] += hA[1] * wv;
        a0[2] += hA[2] * wv; a0[3] += hA[3] * wv;
        a0[4] += hB[0] * wv; a0[5] += hB[1] * wv;
        a0[6] += hB[2] * wv; a0[7] += hB[3] * wv;
    }
    {
        const float b1v = b1[y * DH2 + t];
        const float w2v = W2[y * DH2 + t];
        float p[8];
        #pragma unroll
        for (int m = 0; m < 8; ++m)
            p[m] = fmaxf(a0[m] + b1v, 0.f) * w2v;
        #pragma unroll
        for (int m = 0; m < 8; ++m) {
            float v = p[m];
            for (int off = 32; off > 0; off >>= 1) v += __shfl_down(v, off);
            if (lane == 0) red[w][m] = v;
        }
    }
    __syncthreads();
    if (t < ROWS8) {
        float s = b2[y];
        #pragma unroll
        for (int ww = 0; ww < 8; ++ww) s += red[ww][t];
        out[(size_t)(b0 + t) * NY + y] = s;
    }
}

extern "C" void kernel_launch(void* const* d_in, const int* in_sizes, int n_in,
                              void* d_out, int out_size, void* d_ws, size_t ws_size,
                              hipStream_t stream) {
    const float* x   = (const float*)d_in[0];
    const float* w_x = (const float*)d_in[1];
    const float* w_h = (const float*)d_in[2];
    const float* b   = (const float*)d_in[3];
    const float* W1  = (const float*)d_in[4];
    const float* b1  = (const float*)d_in[5];
    const float* W2  = (const float*)d_in[6];
    const float* b2  = (const float*)d_in[7];
    float* out = (float*)d_out;

    dim3 grid(256), block(512);
    hipLaunchKernelGGL(cwrnn_mfma12, grid, block, 0, stream,
                       x, w_x, w_h, b, W1, b1, W2, b2, out);
}

// Round 14
// 128.632 us; speedup vs baseline: 1.9937x; 1.0970x over previous
//
#include <hip/hip_runtime.h>
#include <math.h>

// Clockwork RNN, B=512 T=192 DX=32 DH1=256 DH2=512 DY=4
// R13 = R12 + two hot-loop diet edits (arithmetic unchanged):
//  1. whole-sequence x pre-pass: all 192 steps of x converted to fp16 in LDS
//     (xpk, 96KB; we are 1 block/CU regardless) -> per-step x term is ONE
//     masked ds_read_b128; kills per-step pkrtz/global-loads/mask VALU.
//  2. batched LDS reads: all 8 h reads + x read hoisted to step top into
//     registers -> single latency exposure before the MFMA burst.
// Kept from R12: lane-half epilogue + carry pre-read, 3 indep MFMA chains,
// s_setprio around MFMA, 256 blocks x 512 thr, fp16 h (PADK=264) dbuf,
// fp16 W registers FULLY UNROLLED (R2 lesson), launch_bounds(512,2)
// (R9/R10 lesson: never force occupancy via bounds).

#define TT    192
#define DXX   32
#define DH1   256
#define DH2   512
#define NY    4
#define ROWS8 8
#define PADK  264   // h row stride in fp16 elems (528B)

typedef _Float16 f16x8 __attribute__((ext_vector_type(8)));
typedef __attribute__((ext_vector_type(4))) float f32x4;
typedef __attribute__((ext_vector_type(2))) int   i32x2;
typedef __attribute__((ext_vector_type(4))) int   i32x4;

template<int N> struct IC { static constexpr int v = N; };

__device__ __forceinline__ unsigned pkrtz(float a, float b) {
    unsigned d;
    asm("v_cvt_pkrtz_f16_f32 %0, %1, %2" : "=v"(d) : "v"(a), "v"(b));
    return d;   // lo16 = f16(a), hi16 = f16(b)
}
__device__ __forceinline__ unsigned short f16bits(_Float16 h) {
    union { _Float16 f; unsigned short u; } c; c.f = h; return c.u;
}
__device__ __forceinline__ float fast_tanh(float v) {
    float t = __builtin_amdgcn_exp2f(v * 2.885390081777927f);
    return fmaf(-2.f, __builtin_amdgcn_rcpf(t + 1.f), 1.f);
}

__global__ __launch_bounds__(512, 2) void cwrnn_mfma13(
    const float* __restrict__ x,     // [B,T,DX]
    const float* __restrict__ w_x,   // [DY,DX,DH1]
    const float* __restrict__ w_h,   // [DY,DH1,DH1]
    const float* __restrict__ bias,  // [DY,DH1]
    const float* __restrict__ W1,    // [DY,DH1,DH2]
    const float* __restrict__ b1,    // [DY,DH2]
    const float* __restrict__ W2,    // [DY,DH2]
    const float* __restrict__ b2,    // [DY]
    float* __restrict__ out)         // [B,DY]
{
    __shared__ _Float16 hb[2][ROWS8 * PADK];   // h fp16, [buf][row][k]
    __shared__ float red[8][ROWS8];
    __shared__ __align__(16) union Pool {
        float scratch[DXX * DH1];              // setup staging / final hT (32KB)
        short xpk[TT * 256];                   // x fp16 [j][rb][k] (96KB)
    } pool;
    __shared__ __align__(16) int xzero[4];     // zero slot for feature mask

    const int t    = threadIdx.x;
    const int lane = t & 63;
    const int w    = t >> 6;        // wave 0..7; tile0 = w, tile1 = 8+w
    const int r    = lane & 15;
    const int rb   = r & 7;         // batch row (r, r+8 duplicate -> broadcast)
    const int q    = lane >> 4;
    const int y    = blockIdx.x & 3;
    const int b0   = (blockIdx.x >> 2) * ROWS8;

    const float* wx_g = w_x + (size_t)y * DXX * DH1;
    const float* wh_g = w_h + (size_t)y * DH1 * DH1;

    for (int i = t; i < ROWS8 * PADK; i += 512) hb[0][i] = (_Float16)0.f;
    if (t < 4) xzero[t] = 0;

    // ---- w_x fragments: wave w -> tiles {w, 8+w}; single fp16 ----
    f16x8 wxf[2];
    for (int i = t * 4; i < DXX * DH1; i += 2048)
        *(f32x4*)&pool.scratch[i] = *(const f32x4*)&wx_g[i];
    __syncthreads();
    #pragma unroll
    for (int m = 0; m < 2; ++m) {
        f16x8 vh;
        #pragma unroll
        for (int jj = 0; jj < 8; ++jj)
            vh[jj] = (_Float16)pool.scratch[(q * 8 + jj) * DH1 + ((m * 8 + w) << 4) + r];
        wxf[m] = vh;
    }
    __syncthreads();

    // ---- w_h fragments: 8 ktiles x 2 mtiles, single fp16. FULLY UNROLLED
    // (runtime index -> scratch demotion; R2 lesson). ----
    f16x8 whf[8][2];
    #pragma unroll
    for (int kt = 0; kt < 8; ++kt) {
        for (int i = t * 4; i < 32 * DH1; i += 2048)
            *(f32x4*)&pool.scratch[i] = *(const f32x4*)&wh_g[kt * 32 * DH1 + i];
        __syncthreads();
        #pragma unroll
        for (int m = 0; m < 2; ++m) {
            f16x8 vh;
            #pragma unroll
            for (int jj = 0; jj < 8; ++jj)
                vh[jj] = (_Float16)pool.scratch[(q * 8 + jj) * DH1 + ((m * 8 + w) << 4) + r];
            whf[kt][m] = vh;
        }
        __syncthreads();
    }

    // ---- x pre-pass: convert all 192 steps to fp16 in LDS (one time) ----
    // xpk[j][rb][k]; idx = rb*768 + j*4 + qq keeps global reads coalesced.
    for (int it = 0; it < 12; ++it) {
        const int idx = t + it * 512;          // < 6144
        const int rbz = idx / 768;
        const int rem = idx - rbz * 768;
        const int j   = rem >> 2;
        const int qq  = idx & 3;
        const float* xp = x + ((size_t)(b0 + rbz) * TT + j) * DXX + qq * 8;
        const f32x4 a = *(const f32x4*)xp;
        const f32x4 b = *(const f32x4*)(xp + 4);
        *(i32x4*)&pool.xpk[j * 256 + rbz * 32 + qq * 8] =
            (i32x4){ (int)pkrtz(a[0], a[1]), (int)pkrtz(a[2], a[3]),
                     (int)pkrtz(b[0], b[1]), (int)pkrtz(b[2], b[3]) };
    }

    f32x4 bias4[2];
    #pragma unroll
    for (int m = 0; m < 2; ++m)
        #pragma unroll
        for (int rr = 0; rr < 4; ++rr)
            bias4[m][rr] = bias[y * DH1 + ((m * 8 + w) << 4) + q * 4 + rr];

    // ---- per-lane LDS pointers ----
    const _Float16* hrd[2] = { &hb[0][rb * PADK] + q * 8,
                               &hb[1][rb * PADK] + q * 8 };
    // lane-half write/carry address: r<8 -> tile w, r>=8 -> tile 8+w
    const int tile_off = ((r < 8) ? w : 8 + w) << 4;
    _Float16* hws[2] = { &hb[0][rb * PADK + tile_off + q * 4],
                         &hb[1][rb * PADK + tile_off + q * 4] };
    const short* xcur = pool.xpk + rb * 32 + q * 8;   // += 1024 per 4 steps
    const short* xz   = (const short*)xzero;

    __syncthreads();   // xpk visible to all

    // ---- one recurrence step ----
    auto body = [&](int jmod, auto SC, int cur) {
        constexpr int S  = SC.v;                       // 0:NC=128 1:192 2:256
        constexpr int NF = (S == 0) ? 16 : (S == 1) ? 24 : 32;
        const bool m1act = (S == 2) || (S == 1 && w < 4);

        // clockwork carry pre-read (old tile1 value, r>=8 lanes use it)
        i32x2 old1;
        if (!m1act) old1 = *(const i32x2*)(hws[cur]);

        // ---- batched reads: 8 h ktiles + x (single latency exposure) ----
        const _Float16* hp = hrd[cur];
        f16x8 hv0 = *(const f16x8*)(hp + 0 * 32);
        f16x8 hv1 = *(const f16x8*)(hp + 1 * 32);
        f16x8 hv2 = *(const f16x8*)(hp + 2 * 32);
        f16x8 hv3 = *(const f16x8*)(hp + 3 * 32);
        f16x8 hv4 = *(const f16x8*)(hp + 4 * 32);
        f16x8 hv5 = *(const f16x8*)(hp + 5 * 32);
        f16x8 hv6 = *(const f16x8*)(hp + 6 * 32);
        f16x8 hv7 = *(const f16x8*)(hp + 7 * 32);
        const short* xptr = (q * 8 < NF) ? (xcur + jmod * 256) : xz;
        const f16x8 xf = *(const f16x8*)xptr;

        // 3 independent chains per tile
        f32x4 c0 = bias4[0], c1 = {0,0,0,0}, c2 = {0,0,0,0};
        f32x4 d0 = bias4[1], d1 = {0,0,0,0}, d2 = {0,0,0,0};

        __builtin_amdgcn_s_setprio(1);
        c0 = __builtin_amdgcn_mfma_f32_16x16x32_f16(whf[0][0], hv0, c0, 0, 0, 0);
        c1 = __builtin_amdgcn_mfma_f32_16x16x32_f16(whf[1][0], hv1, c1, 0, 0, 0);
        c2 = __builtin_amdgcn_mfma_f32_16x16x32_f16(whf[2][0], hv2, c2, 0, 0, 0);
        c0 = __builtin_amdgcn_mfma_f32_16x16x32_f16(whf[3][0], hv3, c0, 0, 0, 0);
        c1 = __builtin_amdgcn_mfma_f32_16x16x32_f16(whf[4][0], hv4, c1, 0, 0, 0);
        c2 = __builtin_amdgcn_mfma_f32_16x16x32_f16(whf[5][0], hv5, c2, 0, 0, 0);
        c0 = __builtin_amdgcn_mfma_f32_16x16x32_f16(whf[6][0], hv6, c0, 0, 0, 0);
        c1 = __builtin_amdgcn_mfma_f32_16x16x32_f16(whf[7][0], hv7, c1, 0, 0, 0);
        c2 = __builtin_amdgcn_mfma_f32_16x16x32_f16(wxf[0],    xf,  c2, 0, 0, 0);
        if (m1act) {
            d0 = __builtin_amdgcn_mfma_f32_16x16x32_f16(whf[0][1], hv0, d0, 0, 0, 0);
            d1 = __builtin_amdgcn_mfma_f32_16x16x32_f16(whf[1][1], hv1, d1, 0, 0, 0);
            d2 = __builtin_amdgcn_mfma_f32_16x16x32_f16(whf[2][1], hv2, d2, 0, 0, 0);
            d0 = __builtin_amdgcn_mfma_f32_16x16x32_f16(whf[3][1], hv3, d0, 0, 0, 0);
            d1 = __builtin_amdgcn_mfma_f32_16x16x32_f16(whf[4][1], hv4, d1, 0, 0, 0);
            d2 = __builtin_amdgcn_mfma_f32_16x16x32_f16(whf[5][1], hv5, d2, 0, 0, 0);
            d0 = __builtin_amdgcn_mfma_f32_16x16x32_f16(whf[6][1], hv6, d0, 0, 0, 0);
            d1 = __builtin_amdgcn_mfma_f32_16x16x32_f16(whf[7][1], hv7, d1, 0, 0, 0);
            d2 = __builtin_amdgcn_mfma_f32_16x16x32_f16(wxf[1],    xf,  d2, 0, 0, 0);
        }
        __builtin_amdgcn_s_setprio(0);

        // ---- epilogue: lane-half tile select -> ONE tanh/pack pipeline ----
        {
            const f32x4 s0 = (c0 + c1) + c2;
            f32x4 sel;
            if (m1act) {
                const f32x4 s1 = (d0 + d1) + d2;
                sel[0] = (r < 8) ? s0[0] : s1[0];
                sel[1] = (r < 8) ? s0[1] : s1[1];
                sel[2] = (r < 8) ? s0[2] : s1[2];
                sel[3] = (r < 8) ? s0[3] : s1[3];
            } else {
                sel = s0;   // r>=8 lanes' value overridden by old1 below
            }
            const unsigned short h0 = f16bits((_Float16)fast_tanh(sel[0]));
            const unsigned short h1 = f16bits((_Float16)fast_tanh(sel[1]));
            const unsigned short h2 = f16bits((_Float16)fast_tanh(sel[2]));
            const unsigned short h3 = f16bits((_Float16)fast_tanh(sel[3]));
            i32x2 wv = (i32x2){ (int)(h0 | ((unsigned)h1 << 16)),
                                (int)(h2 | ((unsigned)h3 << 16)) };
            if (!m1act && r >= 8) wv = old1;   // clockwork carry
            *(i32x2*)(hws[cur ^ 1]) = wv;      // all 64 lanes: unique 8B
        }
        __syncthreads();
    };

    // ---- main loop ----
    for (int j = 0; j < TT; j += 4) {
        body(0, IC<0>{}, 0);   // jp odd           -> NC=128
        body(1, IC<1>{}, 1);   // jp%2==0, %4!=0   -> NC=192
        body(2, IC<0>{}, 0);   // jp odd           -> NC=128
        body(3, IC<2>{}, 1);   // jp%4==0          -> NC=256
        xcur += 1024;
    }
    // final h in buffer 0

    // ---- rebuild h fp32, transposed [k][row] (scratch aliases xpk: loop done) ----
    __syncthreads();
    float* hT = pool.scratch;
    for (int i = t; i < DH1 * ROWS8; i += 512) {
        const int row = i & 7, k = i >> 3;
        hT[k * ROWS8 + row] = (float)hb[0][row * PADK + k];
    }
    __syncthreads();

    // ---- head: hid = relu(h @ W1 + b1); y = hid @ W2 + b2 ----
    const float* W1_g = W1 + (size_t)y * DH1 * DH2;
    float a0[8];
    #pragma unroll
    for (int m = 0; m < 8; ++m) a0[m] = 0.f;
    for (int k = 0; k < DH1; ++k) {
        const float wv = W1_g[(size_t)k * DH2 + t];
        const f32x4 hA = *(const f32x4*)&hT[k * ROWS8];
        const f32x4 hB = *(const f32x4*)&hT[k * ROWS8 + 4];
        a0[0] += hA[0] * wv; a0[1] += hA[1] * wv;
        a0[2] += hA[2] * wv; a0[3] += hA[3] * wv;
        a0[4] += hB[0] * wv; a0[5] += hB[1] * wv;
        a0[6] += hB[2] * wv; a0[7] += hB[3] * wv;
    }
    {
        const float b1v = b1[y * DH2 + t];
        const float w2v = W2[y * DH2 + t];
        float p[8];
        #pragma unroll
        for (int m = 0; m < 8; ++m)
            p[m] = fmaxf(a0[m] + b1v, 0.f) * w2v;
        #pragma unroll
        for (int m = 0; m < 8; ++m) {
            float v = p[m];
            for (int off = 32; off > 0; off >>= 1) v += __shfl_down(v, off);
            if (lane == 0) red[w][m] = v;
        }
    }
    __syncthreads();
    if (t < ROWS8) {
        float s = b2[y];
        #pragma unroll
        for (int ww = 0; ww < 8; ++ww) s += red[ww][t];
        out[(size_t)(b0 + t) * NY + y] = s;
    }
}

extern "C" void kernel_launch(void* const* d_in, const int* in_sizes, int n_in,
                              void* d_out, int out_size, void* d_ws, size_t ws_size,
                              hipStream_t stream) {
    const float* x   = (const float*)d_in[0];
    const float* w_x = (const float*)d_in[1];
    const float* w_h = (const float*)d_in[2];
    const float* b   = (const float*)d_in[3];
    const float* W1  = (const float*)d_in[4];
    const float* b1  = (const float*)d_in[5];
    const float* W2  = (const float*)d_in[6];
    const float* b2  = (const float*)d_in[7];
    float* out = (float*)d_out;

    dim3 grid(256), block(512);
    hipLaunchKernelGGL(cwrnn_mfma13, grid, block, 0, stream,
                       x, w_x, w_h, b, W1, b1, W2, b2, out);
}

// Round 15
// 125.860 us; speedup vs baseline: 2.0376x; 1.0220x over previous
//
#include <hip/hip_runtime.h>
#include <math.h>

// Clockwork RNN, B=512 T=192 DX=32 DH1=256 DH2=512 DY=4
// R14 = R13 + final VALU diet (arithmetic-equivalent):
//  1. 2 MFMA chains (even kt -> c0 w/ bias, odd kt + x -> c1) -> merge halves.
//  2. v_cvt_pkrtz_f16_f32 pair for h write-back (2 ops vs 4 cvt + 2 pack);
//     RTZ bias is noise-like through random-sign W.
// Kept from R13: whole-sequence x pre-pass in LDS, batched h reads, lane-half
// epilogue + carry pre-read, s_setprio, 256 blocks x 512 thr, fp16 h dbuf
// (PADK=264), fp16 W registers FULLY UNROLLED (R2 lesson),
// launch_bounds(512,2) (R9/R10 lesson).

#define TT    192
#define DXX   32
#define DH1   256
#define DH2   512
#define NY    4
#define ROWS8 8
#define PADK  264   // h row stride in fp16 elems (528B)

typedef _Float16 f16x8 __attribute__((ext_vector_type(8)));
typedef __attribute__((ext_vector_type(4))) float f32x4;
typedef __attribute__((ext_vector_type(2))) int   i32x2;
typedef __attribute__((ext_vector_type(4))) int   i32x4;

template<int N> struct IC { static constexpr int v = N; };

__device__ __forceinline__ unsigned pkrtz(float a, float b) {
    unsigned d;
    asm("v_cvt_pkrtz_f16_f32 %0, %1, %2" : "=v"(d) : "v"(a), "v"(b));
    return d;   // lo16 = f16(a), hi16 = f16(b)
}
__device__ __forceinline__ float fast_tanh(float v) {
    float t = __builtin_amdgcn_exp2f(v * 2.885390081777927f);
    return fmaf(-2.f, __builtin_amdgcn_rcpf(t + 1.f), 1.f);
}

__global__ __launch_bounds__(512, 2) void cwrnn_mfma14(
    const float* __restrict__ x,     // [B,T,DX]
    const float* __restrict__ w_x,   // [DY,DX,DH1]
    const float* __restrict__ w_h,   // [DY,DH1,DH1]
    const float* __restrict__ bias,  // [DY,DH1]
    const float* __restrict__ W1,    // [DY,DH1,DH2]
    const float* __restrict__ b1,    // [DY,DH2]
    const float* __restrict__ W2,    // [DY,DH2]
    const float* __restrict__ b2,    // [DY]
    float* __restrict__ out)         // [B,DY]
{
    __shared__ _Float16 hb[2][ROWS8 * PADK];   // h fp16, [buf][row][k]
    __shared__ float red[8][ROWS8];
    __shared__ __align__(16) union Pool {
        float scratch[DXX * DH1];              // setup staging / final hT (32KB)
        short xpk[TT * 256];                   // x fp16 [j][rb][k] (96KB)
    } pool;
    __shared__ __align__(16) int xzero[4];     // zero slot for feature mask

    const int t    = threadIdx.x;
    const int lane = t & 63;
    const int w    = t >> 6;        // wave 0..7; tile0 = w, tile1 = 8+w
    const int r    = lane & 15;
    const int rb   = r & 7;         // batch row (r, r+8 duplicate -> broadcast)
    const int q    = lane >> 4;
    const int y    = blockIdx.x & 3;
    const int b0   = (blockIdx.x >> 2) * ROWS8;

    const float* wx_g = w_x + (size_t)y * DXX * DH1;
    const float* wh_g = w_h + (size_t)y * DH1 * DH1;

    for (int i = t; i < ROWS8 * PADK; i += 512) hb[0][i] = (_Float16)0.f;
    if (t < 4) xzero[t] = 0;

    // ---- w_x fragments: wave w -> tiles {w, 8+w}; single fp16 ----
    f16x8 wxf[2];
    for (int i = t * 4; i < DXX * DH1; i += 2048)
        *(f32x4*)&pool.scratch[i] = *(const f32x4*)&wx_g[i];
    __syncthreads();
    #pragma unroll
    for (int m = 0; m < 2; ++m) {
        f16x8 vh;
        #pragma unroll
        for (int jj = 0; jj < 8; ++jj)
            vh[jj] = (_Float16)pool.scratch[(q * 8 + jj) * DH1 + ((m * 8 + w) << 4) + r];
        wxf[m] = vh;
    }
    __syncthreads();

    // ---- w_h fragments: 8 ktiles x 2 mtiles, single fp16. FULLY UNROLLED
    // (runtime index -> scratch demotion; R2 lesson). ----
    f16x8 whf[8][2];
    #pragma unroll
    for (int kt = 0; kt < 8; ++kt) {
        for (int i = t * 4; i < 32 * DH1; i += 2048)
            *(f32x4*)&pool.scratch[i] = *(const f32x4*)&wh_g[kt * 32 * DH1 + i];
        __syncthreads();
        #pragma unroll
        for (int m = 0; m < 2; ++m) {
            f16x8 vh;
            #pragma unroll
            for (int jj = 0; jj < 8; ++jj)
                vh[jj] = (_Float16)pool.scratch[(q * 8 + jj) * DH1 + ((m * 8 + w) << 4) + r];
            whf[kt][m] = vh;
        }
        __syncthreads();
    }

    // ---- x pre-pass: convert all 192 steps to fp16 in LDS (one time) ----
    for (int it = 0; it < 12; ++it) {
        const int idx = t + it * 512;          // < 6144
        const int rbz = idx / 768;
        const int rem = idx - rbz * 768;
        const int j   = rem >> 2;
        const int qq  = idx & 3;
        const float* xp = x + ((size_t)(b0 + rbz) * TT + j) * DXX + qq * 8;
        const f32x4 a = *(const f32x4*)xp;
        const f32x4 b = *(const f32x4*)(xp + 4);
        *(i32x4*)&pool.xpk[j * 256 + rbz * 32 + qq * 8] =
            (i32x4){ (int)pkrtz(a[0], a[1]), (int)pkrtz(a[2], a[3]),
                     (int)pkrtz(b[0], b[1]), (int)pkrtz(b[2], b[3]) };
    }

    f32x4 bias4[2];
    #pragma unroll
    for (int m = 0; m < 2; ++m)
        #pragma unroll
        for (int rr = 0; rr < 4; ++rr)
            bias4[m][rr] = bias[y * DH1 + ((m * 8 + w) << 4) + q * 4 + rr];

    // ---- per-lane LDS pointers ----
    const _Float16* hrd[2] = { &hb[0][rb * PADK] + q * 8,
                               &hb[1][rb * PADK] + q * 8 };
    const int tile_off = ((r < 8) ? w : 8 + w) << 4;
    _Float16* hws[2] = { &hb[0][rb * PADK + tile_off + q * 4],
                         &hb[1][rb * PADK + tile_off + q * 4] };
    const short* xcur = pool.xpk + rb * 32 + q * 8;   // += 1024 per 4 steps
    const short* xz   = (const short*)xzero;

    __syncthreads();   // xpk visible to all

    // ---- one recurrence step ----
    auto body = [&](int jmod, auto SC, int cur) {
        constexpr int S  = SC.v;                       // 0:NC=128 1:192 2:256
        constexpr int NF = (S == 0) ? 16 : (S == 1) ? 24 : 32;
        const bool m1act = (S == 2) || (S == 1 && w < 4);

        // clockwork carry pre-read (old tile1 value, r>=8 lanes use it)
        i32x2 old1;
        if (!m1act) old1 = *(const i32x2*)(hws[cur]);

        // ---- batched reads: 8 h ktiles + x (single latency exposure) ----
        const _Float16* hp = hrd[cur];
        f16x8 hv0 = *(const f16x8*)(hp + 0 * 32);
        f16x8 hv1 = *(const f16x8*)(hp + 1 * 32);
        f16x8 hv2 = *(const f16x8*)(hp + 2 * 32);
        f16x8 hv3 = *(const f16x8*)(hp + 3 * 32);
        f16x8 hv4 = *(const f16x8*)(hp + 4 * 32);
        f16x8 hv5 = *(const f16x8*)(hp + 5 * 32);
        f16x8 hv6 = *(const f16x8*)(hp + 6 * 32);
        f16x8 hv7 = *(const f16x8*)(hp + 7 * 32);
        const short* xptr = (q * 8 < NF) ? (xcur + jmod * 256) : xz;
        const f16x8 xf = *(const f16x8*)xptr;

        // 2 independent chains per tile: even kt -> c0 (bias), odd kt + x -> c1
        f32x4 c0 = bias4[0], c1 = {0,0,0,0};
        f32x4 d0 = bias4[1], d1 = {0,0,0,0};

        __builtin_amdgcn_s_setprio(1);
        c0 = __builtin_amdgcn_mfma_f32_16x16x32_f16(whf[0][0], hv0, c0, 0, 0, 0);
        c1 = __builtin_amdgcn_mfma_f32_16x16x32_f16(whf[1][0], hv1, c1, 0, 0, 0);
        c0 = __builtin_amdgcn_mfma_f32_16x16x32_f16(whf[2][0], hv2, c0, 0, 0, 0);
        c1 = __builtin_amdgcn_mfma_f32_16x16x32_f16(whf[3][0], hv3, c1, 0, 0, 0);
        c0 = __builtin_amdgcn_mfma_f32_16x16x32_f16(whf[4][0], hv4, c0, 0, 0, 0);
        c1 = __builtin_amdgcn_mfma_f32_16x16x32_f16(whf[5][0], hv5, c1, 0, 0, 0);
        c0 = __builtin_amdgcn_mfma_f32_16x16x32_f16(whf[6][0], hv6, c0, 0, 0, 0);
        c1 = __builtin_amdgcn_mfma_f32_16x16x32_f16(whf[7][0], hv7, c1, 0, 0, 0);
        c1 = __builtin_amdgcn_mfma_f32_16x16x32_f16(wxf[0],    xf,  c1, 0, 0, 0);
        if (m1act) {
            d0 = __builtin_amdgcn_mfma_f32_16x16x32_f16(whf[0][1], hv0, d0, 0, 0, 0);
            d1 = __builtin_amdgcn_mfma_f32_16x16x32_f16(whf[1][1], hv1, d1, 0, 0, 0);
            d0 = __builtin_amdgcn_mfma_f32_16x16x32_f16(whf[2][1], hv2, d0, 0, 0, 0);
            d1 = __builtin_amdgcn_mfma_f32_16x16x32_f16(whf[3][1], hv3, d1, 0, 0, 0);
            d0 = __builtin_amdgcn_mfma_f32_16x16x32_f16(whf[4][1], hv4, d0, 0, 0, 0);
            d1 = __builtin_amdgcn_mfma_f32_16x16x32_f16(whf[5][1], hv5, d1, 0, 0, 0);
            d0 = __builtin_amdgcn_mfma_f32_16x16x32_f16(whf[6][1], hv6, d0, 0, 0, 0);
            d1 = __builtin_amdgcn_mfma_f32_16x16x32_f16(whf[7][1], hv7, d1, 0, 0, 0);
            d1 = __builtin_amdgcn_mfma_f32_16x16x32_f16(wxf[1],    xf,  d1, 0, 0, 0);
        }
        __builtin_amdgcn_s_setprio(0);

        // ---- epilogue: lane-half tile select -> ONE tanh + pkrtz pipeline ----
        {
            const f32x4 s0 = c0 + c1;
            f32x4 sel;
            if (m1act) {
                const f32x4 s1 = d0 + d1;
                sel[0] = (r < 8) ? s0[0] : s1[0];
                sel[1] = (r < 8) ? s0[1] : s1[1];
                sel[2] = (r < 8) ? s0[2] : s1[2];
                sel[3] = (r < 8) ? s0[3] : s1[3];
            } else {
                sel = s0;   // r>=8 lanes' value overridden by old1 below
            }
            const float t0 = fast_tanh(sel[0]), t1 = fast_tanh(sel[1]);
            const float t2 = fast_tanh(sel[2]), t3 = fast_tanh(sel[3]);
            i32x2 wv = (i32x2){ (int)pkrtz(t0, t1), (int)pkrtz(t2, t3) };
            if (!m1act && r >= 8) wv = old1;   // clockwork carry
            *(i32x2*)(hws[cur ^ 1]) = wv;      // all 64 lanes: unique 8B
        }
        __syncthreads();
    };

    // ---- main loop ----
    for (int j = 0; j < TT; j += 4) {
        body(0, IC<0>{}, 0);   // jp odd           -> NC=128
        body(1, IC<1>{}, 1);   // jp%2==0, %4!=0   -> NC=192
        body(2, IC<0>{}, 0);   // jp odd           -> NC=128
        body(3, IC<2>{}, 1);   // jp%4==0          -> NC=256
        xcur += 1024;
    }
    // final h in buffer 0

    // ---- rebuild h fp32, transposed [k][row] (scratch aliases xpk: loop done) ----
    __syncthreads();
    float* hT = pool.scratch;
    for (int i = t; i < DH1 * ROWS8; i += 512) {
        const int row = i & 7, k = i >> 3;
        hT[k * ROWS8 + row] = (float)hb[0][row * PADK + k];
    }
    __syncthreads();

    // ---- head: hid = relu(h @ W1 + b1); y = hid @ W2 + b2 ----
    const float* W1_g = W1 + (size_t)y * DH1 * DH2;
    float a0[8];
    #pragma unroll
    for (int m = 0; m < 8; ++m) a0[m] = 0.f;
    for (int k = 0; k < DH1; ++k) {
        const float wv = W1_g[(size_t)k * DH2 + t];
        const f32x4 hA = *(const f32x4*)&hT[k * ROWS8];
        const f32x4 hB = *(const f32x4*)&hT[k * ROWS8 + 4];
        a0[0] += hA[0] * wv; a0[1] += hA[1] * wv;
        a0[2] += hA[2] * wv; a0[3] += hA[3] * wv;
        a0[4] += hB[0] * wv; a0[5] += hB[1] * wv;
        a0[6] += hB[2] * wv; a0[7] += hB[3] * wv;
    }
    {
        const float b1v = b1[y * DH2 + t];
        const float w2v = W2[y * DH2 + t];
        float p[8];
        #pragma unroll
        for (int m = 0; m < 8; ++m)
            p[m] = fmaxf(a0[m] + b1v, 0.f) * w2v;
        #pragma unroll
        for (int m = 0; m < 8; ++m) {
            float v = p[m];
            for (int off = 32; off > 0; off >>= 1) v += __shfl_down(v, off);
            if (lane == 0) red[w][m] = v;
        }
    }
    __syncthreads();
    if (t < ROWS8) {
        float s = b2[y];
        #pragma unroll
        for (int ww = 0; ww < 8; ++ww) s += red[ww][t];
        out[(size_t)(b0 + t) * NY + y] = s;
    }
}

extern "C" void kernel_launch(void* const* d_in, const int* in_sizes, int n_in,
                              void* d_out, int out_size, void* d_ws, size_t ws_size,
                              hipStream_t stream) {
    const float* x   = (const float*)d_in[0];
    const float* w_x = (const float*)d_in[1];
    const float* w_h = (const float*)d_in[2];
    const float* b   = (const float*)d_in[3];
    const float* W1  = (const float*)d_in[4];
    const float* b1  = (const float*)d_in[5];
    const float* W2  = (const float*)d_in[6];
    const float* b2  = (const float*)d_in[7];
    float* out = (float*)d_out;

    dim3 grid(256), block(512);
    hipLaunchKernelGGL(cwrnn_mfma14, grid, block, 0, stream,
                       x, w_x, w_h, b, W1, b1, W2, b2, out);
}